// Round 2
// baseline (1087.158 us; speedup 1.0000x reference)
//
#include <hip/hip_runtime.h>
#include <stdint.h>

#define NUTT 2048
#define NNODE 2304
#define NE 8128

typedef __attribute__((ext_vector_type(8))) short short8;
typedef __attribute__((ext_vector_type(16))) float float16;

__device__ __forceinline__ float16 MFMA(short8 a, short8 b, float16 c) {
  return __builtin_amdgcn_mfma_f32_32x32x16_bf16(a, b, c, 0, 0, 0);
}

__device__ __forceinline__ unsigned short f2b(float f) {
  unsigned int u = __builtin_bit_cast(unsigned int, f);
  u = (u + 0x7FFFu + ((u >> 16) & 1u)) >> 16;
  return (unsigned short)u;
}
__device__ __forceinline__ float b2f(unsigned short h) {
  unsigned int u = ((unsigned int)h) << 16;
  return __builtin_bit_cast(float, u);
}

// ---------------- workspace offsets (bytes) ----------------
#define OFF_WW   0u
#define OFF_BCNN 19200000u
#define OFF_BGAT 20183040u
#define OFF_BSA  29521920u
#define OFF_BPA  29716480u
#define OFF_WX   29911040u
#define OFF_H16  32368640u   // [2304][312] bf16 (624B rows, cols 300..311 zero)
#define OFF_Z    33806336u   // [2304][3072] bf16 (cols 0..1499 fc, 1500..2999 res)
#define OFF_EL   47962112u
#define OFF_ER   48008192u
#define OFF_CNT  48054272u
#define OFF_CUR  48063488u
#define OFF_PTR  48072704u
#define OFF_EID  48082176u

// ---------------- packing kernels ----------------
__global__ void pack_wordW(const float* __restrict__ src, unsigned short* __restrict__ dst) {
  int i4 = (blockIdx.x * 256 + threadIdx.x) * 4;
  if (i4 >= 9600000) return;
  const float4 v = *(const float4*)(src + i4);
  uint2 o;
  o.x = (unsigned int)f2b(v.x) | ((unsigned int)f2b(v.y) << 16);
  o.y = (unsigned int)f2b(v.z) | ((unsigned int)f2b(v.w) << 16);
  *(uint2*)(dst + i4) = o;
}

__global__ void pack_cnnB(const float* __restrict__ w3, const float* __restrict__ w4,
                          const float* __restrict__ w5, unsigned short* __restrict__ out) {
  int i = blockIdx.x * 256 + threadIdx.x;
  if (i >= 491520) return;
  int width, local; const float* cw;
  if (i < 122880)      { width = 3; local = i;          cw = w3; }
  else if (i < 286720) { width = 4; local = i - 122880; cw = w4; }
  else                 { width = 5; local = i - 286720; cw = w5; }
  int KS = 20 * width;
  int per_nt = KS * 512;
  int nt = local / per_nt;
  int rem = local - nt * per_nt;
  int ks = rem >> 9;
  int lr = rem & 511;
  int lane = lr >> 3, j = lr & 7;
  int col = nt * 32 + (lane & 31);
  int k = ks * 16 + 8 * (lane >> 5) + j;
  int tap = k / 320, koff = k - tap * 320;
  float v = 0.f;
  if (col < 100 && koff < 300) v = cw[(col * width + tap) * 300 + koff];
  out[i] = f2b(v);
}

__global__ void pack_gatB(const float* __restrict__ fc, const float* __restrict__ res,
                          unsigned short* __restrict__ out) {
  int i = blockIdx.x * 256 + threadIdx.x;
  if (i >= 4669440) return;
  int layer = i / 933888;
  int rem = i - layer * 933888;
  int nt = rem / (19 * 512);
  int r2 = rem - nt * (19 * 512);
  int ks = r2 >> 9;
  int lr = r2 & 511;
  int lane = lr >> 3, j = lr & 7;
  int col = nt * 32 + (lane & 31);
  int k = ks * 16 + 8 * (lane >> 5) + j;
  float v = 0.f;
  if (k < 300) {
    if (col < 1500)      v = fc[((size_t)layer * 300 + k) * 1500 + col];
    else if (col < 3000) v = res[((size_t)layer * 300 + k) * 1500 + (col - 1500)];
  }
  out[i] = f2b(v);
}

__global__ void pack_poolB(const float* __restrict__ W, unsigned short* __restrict__ out) {
  int i = blockIdx.x * 256 + threadIdx.x;
  if (i >= 97280) return;
  int nt = i / (19 * 512);
  int r2 = i - nt * (19 * 512);
  int ks = r2 >> 9;
  int lr = r2 & 511;
  int lane = lr >> 3, j = lr & 7;
  int col = nt * 32 + (lane & 31);
  int k = ks * 16 + 8 * (lane >> 5) + j;
  float v = 0.f;
  if (k < 300 && col < 300) v = W[k * 300 + col];
  out[i] = f2b(v);
}

// ---------------- CSR build ----------------
__global__ void csr_zero(int* cnt, int* cur) {
  int i = blockIdx.x * 256 + threadIdx.x;
  if (i < NNODE) { cnt[i] = 0; cur[i] = 0; }
}
__global__ void csr_count(const int* __restrict__ dst, int* cnt) {
  int e = blockIdx.x * 256 + threadIdx.x;
  if (e < NE) atomicAdd(&cnt[dst[e]], 1);
}
__global__ void csr_scan(const int* __restrict__ cnt, int* __restrict__ ptr) {
  __shared__ int part[256];
  __shared__ int loc[NNODE];
  int t = threadIdx.x;
  int s = 0;
  for (int k = 0; k < 9; ++k) { loc[t * 9 + k] = s; s += cnt[t * 9 + k]; }
  part[t] = s;
  __syncthreads();
  for (int off = 1; off < 256; off <<= 1) {
    int add = (t >= off) ? part[t - off] : 0;
    __syncthreads();
    part[t] += add;
    __syncthreads();
  }
  int base = part[t] - s;
  for (int k = 0; k < 9; ++k) ptr[t * 9 + k] = base + loc[t * 9 + k];
  if (t == 255) ptr[NNODE] = part[255];
}
__global__ void csr_scatter(const int* __restrict__ dst, const int* __restrict__ ptr,
                            int* cur, int* __restrict__ eid) {
  int e = blockIdx.x * 256 + threadIdx.x;
  if (e < NE) {
    int d = dst[e];
    int pos = atomicAdd(&cur[d], 1);
    eid[ptr[d] + pos] = e;
  }
}

// ---------------- CNN ----------------
// LDS: A [256][624B] = 159744 | zero pad 64B @159744 | scratch [8][32] f32 @159808 -> 160832
template<int W, int WSEC>
__device__ __forceinline__ void cnn_section(const char* sm, float* scratch,
    const unsigned short* Bsec, const float* bias, float* wxrow, int tid) {
  int lane = tid & 63, wave = tid >> 6;
  int l31 = lane & 31, g = lane >> 5;
  int Mblk = wave >> 2, nt = wave & 3;
  const int KS = 20 * W;
  float16 acc[4] = {};
  const char* bptr = (const char*)Bsec + (size_t)(nt * KS) * 1024 + lane * 16;
  int rbase = Mblk * 128 + l31;
  for (int j = 0; j < W; ++j) {
    int q0 = rbase + j;       q0 = (q0 > 255 ? 255 : q0) * 624;
    int q1 = rbase + 32 + j;  q1 = (q1 > 255 ? 255 : q1) * 624;
    int q2 = rbase + 64 + j;  q2 = (q2 > 255 ? 255 : q2) * 624;
    int q3 = rbase + 96 + j;  q3 = (q3 > 255 ? 255 : q3) * 624;
    #pragma unroll 4
    for (int kl = 0; kl < 20; ++kl) {
      int kb = kl * 32 + 16 * g;
      short8 a0 = *(const short8*)(sm + q0 + kb);
      short8 a1 = *(const short8*)(sm + q1 + kb);
      short8 a2 = *(const short8*)(sm + q2 + kb);
      short8 a3 = *(const short8*)(sm + q3 + kb);
      short8 bb = *(const short8*)(bptr);
      bptr += 1024;
      acc[0] = MFMA(a0, bb, acc[0]);
      acc[1] = MFMA(a1, bb, acc[1]);
      acc[2] = MFMA(a2, bb, acc[2]);
      acc[3] = MFMA(a3, bb, acc[3]);
    }
  }
  float cm = -3.0e38f;
  #pragma unroll
  for (int mt = 0; mt < 4; ++mt) {
    #pragma unroll
    for (int r = 0; r < 16; ++r) {
      int row = Mblk * 128 + mt * 32 + (r & 3) + 8 * (r >> 2) + 4 * g;
      float v = acc[mt][r];
      if (row <= 256 - W && v > cm) cm = v;
    }
  }
  cm = fmaxf(cm, __shfl_xor(cm, 32));
  if (lane < 32) scratch[(Mblk * 4 + nt) * 32 + lane] = cm;
  __syncthreads();
  if (tid < 128) {
    int ntt = tid >> 5, c = tid & 31;
    int f = ntt * 32 + c;
    if (f < 100) {
      float v = fmaxf(scratch[ntt * 32 + c], scratch[(4 + ntt) * 32 + c]);
      wxrow[WSEC * 100 + f] = v + bias[f];
    }
  }
  __syncthreads();
}

__global__ __launch_bounds__(512, 2) void cnn_kernel(
    const int* __restrict__ x, const unsigned short* __restrict__ wW,
    const unsigned short* __restrict__ Bcnn,
    const float* __restrict__ cb3, const float* __restrict__ cb4, const float* __restrict__ cb5,
    float* __restrict__ wx) {
  extern __shared__ char sm[];
  int n = blockIdx.x, tid = threadIdx.x;
  float* scratch = (float*)(sm + 159808);
  if (tid < 16) *(int*)(sm + 159744 + tid * 4) = 0;
  const int* xr = x + n * 256;
  for (int i = tid; i < 19968; i += 512) {   // 256 rows * 78 chunks (8B)
    int r = i / 78, c = i - r * 78;
    uint2 v; v.x = 0u; v.y = 0u;
    if (c < 75) {
      int tok = xr[r];
      v = *(const uint2*)((const char*)wW + (size_t)tok * 600 + c * 8);
    }
    *(uint2*)(sm + r * 624 + c * 8) = v;
  }
  __syncthreads();
  float* wxrow = wx + (size_t)n * 300;
  cnn_section<3, 0>(sm, scratch, Bcnn,           cb3, wxrow, tid);
  cnn_section<4, 1>(sm, scratch, Bcnn + 122880,  cb4, wxrow, tid);
  cnn_section<5, 2>(sm, scratch, Bcnn + 286720,  cb5, wxrow, tid);
}

// ---------------- feature assembly ----------------
__global__ void feat_kernel(const float* __restrict__ wx, const float* __restrict__ posW,
                            const int* __restrict__ lid, const float* __restrict__ partyW,
                            const int* __restrict__ pids, const int* __restrict__ u_idx,
                            const int* __restrict__ q_idx, unsigned short* __restrict__ h16) {
  int b = blockIdx.x, t = threadIdx.x;
  int node = (b < NUTT) ? u_idx[b] : q_idx[b - NUTT];
  for (int d = t; d < 312; d += 64) {
    float v = 0.f;
    if (d < 300)
      v = (b < NUTT) ? (wx[(size_t)b * 300 + d] + posW[(size_t)lid[b] * 300 + d])
                     : partyW[(size_t)pids[b - NUTT] * 300 + d];
    h16[(size_t)node * 312 + d] = (d < 300) ? f2b(v) : (unsigned short)0;
  }
}

// ---------------- GAT GEMM: z|res = h @ [fc|res] ----------------
__global__ __launch_bounds__(512, 2) void gat_mm(
    const unsigned short* __restrict__ h16, const unsigned short* __restrict__ Bg,
    unsigned short* __restrict__ z) {
  extern __shared__ char sm[];   // 128 rows * 624B = 79872
  int tid = threadIdx.x, lane = tid & 63, wave = tid >> 6;
  int WGm = blockIdx.x, WGn = blockIdx.y;
  const char* srcp = (const char*)h16 + (size_t)WGm * 79872;
  for (int i = tid; i < 4992; i += 512)
    *(uint4*)(sm + i * 16) = *(const uint4*)(srcp + (size_t)i * 16);
  __syncthreads();
  int l31 = lane & 31, g = lane >> 5;
  int Mblk = wave >> 2, Nblk = wave & 3;
  float16 acc[2][2] = {};
  const char* a0 = sm + (Mblk * 64 + l31) * 624 + 16 * g;
  const char* a1 = a0 + 32 * 624;
  // B n-tile index must include the workgroup's N offset (WGn*8 tiles of 32)
  const char* b0 = (const char*)Bg + (size_t)((WGn * 8 + Nblk * 2) * 19) * 1024 + lane * 16;
  const char* b1 = b0 + 19 * 1024;
  #pragma unroll 2
  for (int ks = 0; ks < 19; ++ks) {
    short8 A0 = *(const short8*)(a0 + ks * 32);
    short8 A1 = *(const short8*)(a1 + ks * 32);
    short8 B0 = *(const short8*)(b0 + (size_t)ks * 1024);
    short8 B1 = *(const short8*)(b1 + (size_t)ks * 1024);
    acc[0][0] = MFMA(A0, B0, acc[0][0]);
    acc[0][1] = MFMA(A0, B1, acc[0][1]);
    acc[1][0] = MFMA(A1, B0, acc[1][0]);
    acc[1][1] = MFMA(A1, B1, acc[1][1]);
  }
  #pragma unroll
  for (int mi = 0; mi < 2; ++mi)
    #pragma unroll
    for (int ni = 0; ni < 2; ++ni)
      #pragma unroll
      for (int r = 0; r < 16; ++r) {
        int row = WGm * 128 + Mblk * 64 + mi * 32 + (r & 3) + 8 * (r >> 2) + 4 * g;
        int col = WGn * 256 + (Nblk * 2 + ni) * 32 + l31;
        z[(size_t)row * 3072 + col] = f2b(acc[mi][ni][r]);
      }
}

// ---------------- GAT edge kernels ----------------
__global__ void gat_edge1(const unsigned short* __restrict__ z,
                          const float* __restrict__ al, const float* __restrict__ ar,
                          float* __restrict__ el, float* __restrict__ er) {
  int node = blockIdx.x * 4 + (threadIdx.x >> 6);
  if (node >= NNODE) return;
  int lane = threadIdx.x & 63;
  for (int h = 0; h < 5; ++h) {
    float accl = 0.f, accr = 0.f;
    for (int d = lane; d < 300; d += 64) {
      float zv = b2f(z[(size_t)node * 3072 + h * 300 + d]);
      accl += zv * al[h * 300 + d];
      accr += zv * ar[h * 300 + d];
    }
    for (int s = 32; s; s >>= 1) {
      accl += __shfl_xor(accl, s);
      accr += __shfl_xor(accr, s);
    }
    if (lane == 0) { el[node * 5 + h] = accl; er[node * 5 + h] = accr; }
  }
}

__global__ __launch_bounds__(320) void gat_edge2(
    const unsigned short* __restrict__ z, const float* __restrict__ el,
    const float* __restrict__ er, const float* __restrict__ gb,
    const int* __restrict__ ptr, const int* __restrict__ eidl,
    const int* __restrict__ srcA, unsigned short* __restrict__ h16out) {
  int dstn = blockIdx.x;
  int tid = threadIdx.x, h = tid >> 6, lane = tid & 63;
  __shared__ float lds5[5][304];
  int p0 = ptr[dstn], deg = ptr[dstn + 1] - p0;
  float ee = 0.f, den = 0.f;
  int sj = 0;
  if (deg > 0) {
    float s = -3.0e38f;
    if (lane < deg) {
      int e = eidl[p0 + lane];
      sj = srcA[e];
      float sv = el[sj * 5 + h] + er[dstn * 5 + h];
      s = (sv >= 0.f) ? sv : 0.2f * sv;
    }
    float m = s;
    for (int t = 32; t; t >>= 1) m = fmaxf(m, __shfl_xor(m, t));
    ee = (lane < deg) ? __expf(s - m) : 0.f;
    den = ee;
    for (int t = 32; t; t >>= 1) den += __shfl_xor(den, t);
  }
  for (int it = 0; it < 5; ++it) {
    int d = lane + it * 64;
    float acc = 0.f;
    if (deg > 0) {
      for (int e = 0; e < deg; ++e) {
        float w = __shfl(ee, e);
        int srow = __shfl(sj, e);
        if (d < 300) acc += w * b2f(z[(size_t)srow * 3072 + h * 300 + d]);
      }
      acc /= den;
    }
    if (d < 300) {
      float res = b2f(z[(size_t)dstn * 3072 + 1500 + h * 300 + d]);
      lds5[h][d] = acc + res + gb[h * 300 + d];
    }
  }
  __syncthreads();
  if (tid < 312) {
    float v = 0.f;
    if (tid < 300)
      v = 0.2f * (lds5[0][tid] + lds5[1][tid] + lds5[2][tid] + lds5[3][tid] + lds5[4][tid]);
    h16out[(size_t)dstn * 312 + tid] = (tid < 300) ? f2b(v) : (unsigned short)0;
  }
}

// ---------------- pooling + head ----------------
__device__ __forceinline__ void ctx_attn(const char* XB, int mtiles, int Kvalid,
    const unsigned short* Bw, const float* bias, const float* cvec,
    float* T, float* AA, float* OUT, int tid) {
  int lane = tid & 63, wave = tid >> 6;
  int l31 = lane & 31, g = lane >> 5;
  int ntasks = mtiles * 10;
  for (int t = wave; t < ntasks; t += 8) {
    int nt, mt;
    if (mtiles == 2) { nt = t >> 1; mt = t & 1; } else { nt = t; mt = 0; }
    float16 acc = {};
    const char* ap = XB + (mt * 32 + l31) * 624 + 16 * g;
    const char* bp = (const char*)Bw + (size_t)(nt * 19) * 1024 + lane * 16;
    for (int ks = 0; ks < 19; ++ks) {
      short8 A = *(const short8*)(ap + ks * 32);
      short8 Bv = *(const short8*)(bp + (size_t)ks * 1024);
      acc = MFMA(A, Bv, acc);
    }
    int col = nt * 32 + l31;
    if (col < 300) {
      float bc = bias[col];
      #pragma unroll
      for (int r = 0; r < 16; ++r) {
        int row = mt * 32 + (r & 3) + 8 * (r >> 2) + 4 * g;
        T[row * 305 + col] = tanhf(acc[r] + bc);
      }
    }
  }
  __syncthreads();
  if (tid < 64) {
    float lg = -3.0e38f;
    if (tid < Kvalid) {
      lg = 0.f;
      for (int d = 0; d < 300; ++d) lg += T[tid * 305 + d] * cvec[d];
    }
    AA[tid] = lg;
  }
  __syncthreads();
  if (wave == 0) {
    float v = AA[lane];
    float m = v;
    for (int s2 = 32; s2; s2 >>= 1) m = fmaxf(m, __shfl_xor(m, s2));
    float e = (lane < Kvalid) ? __expf(v - m) : 0.f;
    float s = e;
    for (int s2 = 32; s2; s2 >>= 1) s += __shfl_xor(s, s2);
    AA[lane] = e / s;
  }
  __syncthreads();
  if (tid < 300) {
    float acc = 0.f;
    for (int k = 0; k < Kvalid; ++k)
      acc += AA[k] * b2f(*(const unsigned short*)(XB + k * 624 + tid * 2));
    OUT[tid] = acc;
  }
  __syncthreads();
}

__global__ __launch_bounds__(512) void pool_kernel(
    const unsigned short* __restrict__ h16,
    const int* __restrict__ u_idx, const int* __restrict__ q_idx,
    const float* __restrict__ py,
    const unsigned short* __restrict__ Bsa, const unsigned short* __restrict__ Bpa,
    const float* __restrict__ sab, const float* __restrict__ sac,
    const float* __restrict__ pab, const float* __restrict__ pac,
    const float* __restrict__ vW, const float* __restrict__ vb,
    const float* __restrict__ outW, const float* __restrict__ outb,
    float* __restrict__ dout) {
  extern __shared__ char sm[];
  int b = blockIdx.x, tid = threadIdx.x;
  char* HU = sm;                       // 39936
  char* HQ = sm + 39936;               // 19968 -> 59904
  float* T   = (float*)(sm + 59904);   // 64*305*4 = 78080 -> 137984
  float* AA  = (float*)(sm + 137984);  // 256 -> 138240
  float* PX  = (float*)(sm + 138240);  // 1216 -> 139456
  float* SX  = (float*)(sm + 139456);  // 1216 -> 140672
  float* RED = (float*)(sm + 140672);  // 2048 -> 142720
  for (int i = tid; i < 64 * 78; i += 512) {
    int r = i / 78, c = i - r * 78;
    int node = u_idx[b * 64 + r];
    *(uint2*)(HU + r * 624 + c * 8) =
        *(const uint2*)((const char*)h16 + (size_t)node * 624 + c * 8);
  }
  for (int i = tid; i < 32 * 78; i += 512) {
    int r = i / 78, c = i - r * 78;
    uint2 v; v.x = 0u; v.y = 0u;
    if (r < 8) {
      int node = q_idx[b * 8 + r];
      v = *(const uint2*)((const char*)h16 + (size_t)node * 624 + c * 8);
    }
    *(uint2*)(HQ + r * 624 + c * 8) = v;
  }
  __syncthreads();
  ctx_attn(HU, 2, 64, Bsa, sab, sac, T, AA, SX, tid);
  ctx_attn(HQ, 1, 8,  Bpa, pab, pac, T, AA, PX, tid);
  float contrib = 0.f;
  if (tid < 300) {
    float pv = py[b] * vW[tid] + vb[tid];
    contrib = PX[tid] * outW[tid] + SX[tid] * outW[300 + tid] + pv * outW[600 + tid];
  }
  RED[tid] = contrib;
  __syncthreads();
  for (int s = 256; s > 0; s >>= 1) {
    if (tid < s) RED[tid] += RED[tid + s];
    __syncthreads();
  }
  if (tid == 0) dout[b] = RED[0] + outb[0];
}

// ---------------- launcher ----------------
extern "C" void kernel_launch(void* const* d_in, const int* in_sizes, int n_in,
                              void* d_out, int out_size, void* d_ws, size_t ws_size,
                              hipStream_t stream) {
  (void)in_sizes; (void)n_in; (void)out_size; (void)ws_size;
  const int*   x       = (const int*)d_in[0];
  const int*   srcA    = (const int*)d_in[1];
  const int*   dstA    = (const int*)d_in[2];
  const int*   u_idx   = (const int*)d_in[3];
  const int*   q_idx   = (const int*)d_in[4];
  const int*   lid     = (const int*)d_in[5];
  const int*   pids    = (const int*)d_in[6];
  const float* py      = (const float*)d_in[7];
  const float* word_W  = (const float*)d_in[8];
  const float* cw3     = (const float*)d_in[9];
  const float* cb3     = (const float*)d_in[10];
  const float* cw4     = (const float*)d_in[11];
  const float* cb4     = (const float*)d_in[12];
  const float* cw5     = (const float*)d_in[13];
  const float* cb5     = (const float*)d_in[14];
  const float* party_W = (const float*)d_in[15];
  const float* pos_W   = (const float*)d_in[16];
  const float* gat_fc  = (const float*)d_in[17];
  const float* gat_al  = (const float*)d_in[18];
  const float* gat_ar  = (const float*)d_in[19];
  const float* gat_res = (const float*)d_in[20];
  const float* gat_b   = (const float*)d_in[21];
  const float* pa_W    = (const float*)d_in[22];
  const float* pa_b    = (const float*)d_in[23];
  const float* pa_c    = (const float*)d_in[24];
  const float* sa_W    = (const float*)d_in[25];
  const float* sa_b    = (const float*)d_in[26];
  const float* sa_c    = (const float*)d_in[27];
  const float* v_W     = (const float*)d_in[28];
  const float* v_b     = (const float*)d_in[29];
  const float* out_W   = (const float*)d_in[30];
  const float* out_b   = (const float*)d_in[31];

  char* ws = (char*)d_ws;
  unsigned short* wW16 = (unsigned short*)(ws + OFF_WW);
  unsigned short* Bcnn = (unsigned short*)(ws + OFF_BCNN);
  unsigned short* Bgat = (unsigned short*)(ws + OFF_BGAT);
  unsigned short* Bsa  = (unsigned short*)(ws + OFF_BSA);
  unsigned short* Bpa  = (unsigned short*)(ws + OFF_BPA);
  float*          wx   = (float*)(ws + OFF_WX);
  unsigned short* h16  = (unsigned short*)(ws + OFF_H16);
  unsigned short* z    = (unsigned short*)(ws + OFF_Z);
  float*          el   = (float*)(ws + OFF_EL);
  float*          er   = (float*)(ws + OFF_ER);
  int*            cnt  = (int*)(ws + OFF_CNT);
  int*            cur  = (int*)(ws + OFF_CUR);
  int*            ptr  = (int*)(ws + OFF_PTR);
  int*            eid  = (int*)(ws + OFF_EID);

  (void)hipFuncSetAttribute((const void*)cnn_kernel,
      hipFuncAttributeMaxDynamicSharedMemorySize, 160832);
  (void)hipFuncSetAttribute((const void*)gat_mm,
      hipFuncAttributeMaxDynamicSharedMemorySize, 79872);
  (void)hipFuncSetAttribute((const void*)pool_kernel,
      hipFuncAttributeMaxDynamicSharedMemorySize, 142720);

  pack_wordW<<<dim3(9375), dim3(256), 0, stream>>>(word_W, wW16);
  pack_cnnB<<<dim3(1920), dim3(256), 0, stream>>>(cw3, cw4, cw5, Bcnn);
  pack_gatB<<<dim3(18240), dim3(256), 0, stream>>>(gat_fc, gat_res, Bgat);
  pack_poolB<<<dim3(380), dim3(256), 0, stream>>>(sa_W, Bsa);
  pack_poolB<<<dim3(380), dim3(256), 0, stream>>>(pa_W, Bpa);

  csr_zero<<<dim3(9), dim3(256), 0, stream>>>(cnt, cur);
  csr_count<<<dim3(32), dim3(256), 0, stream>>>(dstA, cnt);
  csr_scan<<<dim3(1), dim3(256), 0, stream>>>(cnt, ptr);
  csr_scatter<<<dim3(32), dim3(256), 0, stream>>>(dstA, ptr, cur, eid);

  cnn_kernel<<<dim3(2048), dim3(512), 160832, stream>>>(x, wW16, Bcnn, cb3, cb4, cb5, wx);
  feat_kernel<<<dim3(NNODE), dim3(64), 0, stream>>>(wx, pos_W, lid, party_W, pids,
                                                    u_idx, q_idx, h16);
  for (int l = 0; l < 5; ++l) {
    gat_mm<<<dim3(18, 12), dim3(512), 79872, stream>>>(h16, Bgat + (size_t)l * 933888, z);
    gat_edge1<<<dim3(576), dim3(256), 0, stream>>>(z, gat_al + l * 1500, gat_ar + l * 1500,
                                                   el, er);
    gat_edge2<<<dim3(NNODE), dim3(320), 0, stream>>>(z, el, er, gat_b + l * 1500,
                                                     ptr, eid, srcA, h16);
  }
  pool_kernel<<<dim3(32), dim3(512), 142720, stream>>>(
      h16, u_idx, q_idx, py, Bsa, Bpa, sa_b, sa_c, pa_b, pa_c,
      v_W, v_b, out_W, out_b, (float*)d_out);
}